// Round 6
// baseline (223.144 us; speedup 1.0000x reference)
//
#include <hip/hip_runtime.h>
#include <cstdint>

// StreamNet K3 S1 halo conv, bf16 MFMA implicit-GEMM.
// R11 = R9's proven staging structure + 4 blocks/CU + pinned occupancy.
// History: R9 (all-loads-up-front, 2 blk/CU, 96 VGPR, no spill) = 43.3us,
// BW 2.43 TB/s. R7/R8b/R10 all regressed the same way: with launch_bounds
// min-waves 3 or 4, the RA voluntarily squeezes VGPRs (84/64) below the
// ~116-reg live set to chase reg-occupancy the LDS cap makes unreachable,
// spilling ~60MB of scratch traffic. Fix: amdgpu_waves_per_eu(4,4) pins the
// budget at exactly 128 regs (no squeeze) AND LDS shrunk to 39168B (RS 36->34
// by dropping the left-pad column, PL 652->612) -> 4 blocks/CU resident.
// 4 independent blocks per CU stagger their memory bursts across each
// other's compute tails -> duty-cycle fix (R9 fact: fill kernel hits
// 6.3 TB/s at 8.7% occupancy, so the 2.45 wall is duty cycle, not depth).
// Interior LDS stores are ds_write_b64 pairs now (col offset 2 mod 4 dw).
// Keeps: pack_w prologue (R10: repack VALU + W traffic out of the hot
// kernel; conflicts 1.5M->328K), 16x32 tiles (128B rows), grid 1024,
// XCD swizzle (batch i -> XCD i), ch-split MFMA sweep, plain f4 stores.
//
// Padded input Xp[b][c][r][cc], r,cc in [0,258):
//   r < 2           -> bbuf[b][c][r][cc]           (bbuf [B][C][2][258])
//   r>=2, cc < 2    -> rbuf[b][c][r-2][cc]         (rbuf [B][C][256][2])
//   r>=2, cc>=2     -> (cc-2 == 255) ? 0 : x[b][c][r-2][cc-2]

constexpr int B  = 8;
constexpr int C  = 32;
constexpr int P  = 256;
constexpr int KB = 2;
constexpr int TH = 16;            // tile rows
constexpr int TW = 32;            // tile cols
constexpr int RS = 34;            // LDS row stride (dwords) == padded width, no pad col
constexpr int PL = 612;           // plane stride (dwords); 4q*612 mod 32 = {0,16} -> 2-way, free
constexpr int XSZ = 16 * PL;      // 9792 dwords = 39168 B -> 4 blocks/CU (low 4608 dw: W overlay)

typedef short bf16x8 __attribute__((ext_vector_type(8)));
typedef float f32x4  __attribute__((ext_vector_type(4)));
union Frag { uint32_t u[4]; bf16x8 v; };

static __device__ __forceinline__ uint32_t pk_bf16(float lo, float hi) {
    uint32_t a  = __builtin_bit_cast(uint32_t, lo);
    uint32_t b2 = __builtin_bit_cast(uint32_t, hi);
    a  += 0x7FFFu + ((a  >> 16) & 1u);
    b2 += 0x7FFFu + ((b2 >> 16) & 1u);
    return (a >> 16) | (b2 & 0xFFFF0000u);
}

// ---- prologue: pack W [C][C][3][3] f32 -> bf16-pair LDS image in d_ws ----
// image dword index: t*512 + oc*16 + icpair, halves (lo,hi) = ic (2m, 2m+1)
__global__ __launch_bounds__(256) void pack_w_kernel(
    const float* __restrict__ W, uint32_t* __restrict__ wpk)
{
    const int g = blockIdx.x * 256 + threadIdx.x;      // 0..2303
    const float4 v = ((const float4*)W)[g];
    const float vv[4] = { v.x, v.y, v.z, v.w };
    uint16_t* wh = (uint16_t*)wpk;
    #pragma unroll
    for (int e = 0; e < 4; ++e) {
        const int flat = 4 * g + e;                    // (oc*32+ic)*9 + t
        const int t    = flat % 9;
        const int rest = flat / 9;
        const int ic   = rest & 31;
        const int oc   = rest >> 5;
        const uint32_t u = __builtin_bit_cast(uint32_t, vv[e]);
        const uint16_t h = (uint16_t)((u + 0x7FFFu + ((u >> 16) & 1u)) >> 16);
        wh[(t * 512 + oc * 16 + (ic >> 1)) * 2 + (ic & 1)] = h;
    }
}

struct StP {                       // one plane-pair's staged data
    float4 a0, a1, c0, c1;         // interior: lo plane 8 cols, hi plane 8 cols
    float  h0l, h0h, h1l, h1h;     // 2 halo cells x (lo, hi)
};

__global__
__attribute__((amdgpu_flat_work_group_size(256, 256)))
__attribute__((amdgpu_waves_per_eu(4, 4)))          // pin: exactly 128-VGPR budget
void conv_mfma(
    const float* __restrict__ x,      // [B][C][P][P]
    const float* __restrict__ rbuf,   // [B][C][P][KB]
    const float* __restrict__ bbuf,   // [B][C][KB][P+KB]
    const uint32_t* __restrict__ wpk, // packed W image (4608 dwords)
    const float* __restrict__ bias,   // [C]
    float* __restrict__ out)          // [B][C][P][P]
{
    const int tid  = threadIdx.x;
    const int lane = tid & 63;
    const int w    = tid >> 6;        // wave 0..3
    const int q    = lane >> 4;
    const int n16  = lane & 15;

    // XCD swizzle: round-robin dispatch (blk%8 = XCD) -> XCD i gets swz
    // range [128i,128(i+1)) = all tiles of batch i (8.4MB x, in-XCD halos)
    const int swz = (blockIdx.x & 7) * 128 + (blockIdx.x >> 3);
    const int cx = swz & 7, ty = (swz >> 3) & 15, b = swz >> 7;
    const int x0 = cx * TW, y0 = ty * TH;

    __shared__ uint32_t Xs[XSZ];      // low 4608 dwords double as W region first

    // ---- staging lane geometry ----
    const int srow = lane >> 2;                    // 0..15
    const int scol = (lane & 3) * 8;               // 0,8,16,24 (8 cols/lane)
    const bool zc  = (x0 == P - TW) && ((lane & 3) == 3);   // col 255 in a1.w/c1.w

    // halo cells: 100 = top 2x34 (idx 0..67) + left 16x2 (idx 68..99)
    const float* xb = x    + (size_t)b * C * P * P;
    const float* rb = rbuf + (size_t)b * C * P * KB;
    const float* bb = bbuf + (size_t)b * C * KB * (P + KB);
    const float* basep[3] = { xb, rb, bb };
    const int    psz[3]   = { P * P, P * KB, KB * (P + KB) };

    int h_ldso[2], h_ps[2];
    const float* h_bp[2];
    bool h_z[2];
    #pragma unroll
    for (int ci = 0; ci < 2; ++ci) {
        const int c = lane + 64 * ci;
        int prow, pcol;
        if (c < 68) { const int hr = (c >= 34) ? 1 : 0; prow = hr; pcol = c - 34 * hr; }
        else        { const int cc = c - 68; prow = KB + (cc >> 1); pcol = cc & 1; }
        h_ldso[ci] = prow * RS + pcol;             // padded col pc at dword pc now
        const int gr = y0 + prow, gc = x0 + pcol;
        int sel, off; bool z = false;
        if (gr < KB)      { sel = 2; off = gr * (P + KB) + gc; }
        else if (gc < KB) { sel = 1; off = (gr - KB) * KB + gc; }
        else              { sel = 0; off = (gr - KB) * P + (gc - KB); z = (gc == P + KB - 1); }
        h_bp[ci] = basep[sel] + off;
        h_ps[ci] = psz[sel];
        h_z[ci]  = z;
    }
    const bool h1a = lane < 36;                    // cell1 active

    // ---- 1. W image loads FIRST (their ds_write waits only on them) ----
    const uint4* wp4 = (const uint4*)wpk;          // 1152 uint4
    uint4 wv0 = wp4[tid];
    uint4 wv1 = wp4[256 + tid];
    uint4 wv2 = wp4[512 + tid];
    uint4 wv3 = wp4[768 + tid];
    uint4 wvt;
    const bool wtail = tid < 128;
    if (wtail) wvt = wp4[1024 + tid];
    const float bv0 = bias[n16];
    const float bv1 = bias[16 + n16];

    // ---- 2. issue ALL X loads (R9 structure: deep one-shot queue) ----
    StP S[4];
    #pragma unroll
    for (int k2 = 0; k2 < 4; ++k2) {
        const int m = 4 * k2 + w;
        const float* pi = xb + (size_t)(2 * m) * (P * P) + (y0 + srow) * P + x0 + scol;
        S[k2].a0 = *(const float4*)pi;
        S[k2].a1 = *(const float4*)(pi + 4);
        S[k2].c0 = *(const float4*)(pi + P * P);
        S[k2].c1 = *(const float4*)(pi + P * P + 4);
        const float* p0 = h_bp[0] + (size_t)(2 * m) * h_ps[0];
        S[k2].h0l = h_z[0] ? 0.f : p0[0];
        S[k2].h0h = h_z[0] ? 0.f : p0[h_ps[0]];
        if (h1a) {
            const float* p1 = h_bp[1] + (size_t)(2 * m) * h_ps[1];
            S[k2].h1l = h_z[1] ? 0.f : p1[0];
            S[k2].h1h = h_z[1] ? 0.f : p1[h_ps[1]];
        }
    }

    // ---- 3. W image -> LDS overlay (vmcnt waits only to W loads) ----
    uint4* xs4 = (uint4*)Xs;
    xs4[tid]       = wv0;
    xs4[256 + tid] = wv1;
    xs4[512 + tid] = wv2;
    xs4[768 + tid] = wv3;
    if (wtail) xs4[1024 + tid] = wvt;
    __syncthreads();

    // ---- 4. B fragments from overlay (X loads still draining) ----
    Frag Bf[9][2];
    #pragma unroll
    for (int t = 0; t < 9; ++t)
        #pragma unroll
        for (int oh = 0; oh < 2; ++oh)
            *(uint4*)Bf[t][oh].u =
                *(const uint4*)&Xs[t * 512 + (oh * 16 + n16) * 16 + q * 4];
    __syncthreads();              // overlay reads done; Xs reusable for X tile

    // ---- 5. pack + store X tiles (b64 stores: col offset 2 mod 4 dw) ----
    #pragma unroll
    for (int k2 = 0; k2 < 4; ++k2) {
        const int m = 4 * k2 + w;
        float4 a1 = S[k2].a1, c1 = S[k2].c1;
        if (zc) { a1.w = 0.f; c1.w = 0.f; }
        uint2 p0, p1, p2, p3;
        p0.x = pk_bf16(S[k2].a0.x, S[k2].c0.x); p0.y = pk_bf16(S[k2].a0.y, S[k2].c0.y);
        p1.x = pk_bf16(S[k2].a0.z, S[k2].c0.z); p1.y = pk_bf16(S[k2].a0.w, S[k2].c0.w);
        p2.x = pk_bf16(a1.x, c1.x);             p2.y = pk_bf16(a1.y, c1.y);
        p3.x = pk_bf16(a1.z, c1.z);             p3.y = pk_bf16(a1.w, c1.w);
        uint32_t* base = Xs + m * PL + (srow + KB) * RS + KB + scol;  // 8B aligned
        *(uint2*)(base + 0) = p0;
        *(uint2*)(base + 2) = p1;
        *(uint2*)(base + 4) = p2;
        *(uint2*)(base + 6) = p3;
        Xs[m * PL + h_ldso[0]] = pk_bf16(S[k2].h0l, S[k2].h0h);
        if (h1a) Xs[m * PL + h_ldso[1]] = pk_bf16(S[k2].h1l, S[k2].h1h);
    }
    __syncthreads();

    // ---- 6. MFMA sweep, split by column-half ch (acc stays 32 f32) ----
    #pragma unroll
    for (int ch = 0; ch < 2; ++ch) {
        f32x4 acc[4][2];
        #pragma unroll
        for (int rr = 0; rr < 4; ++rr)
            #pragma unroll
            for (int oh = 0; oh < 2; ++oh)
                #pragma unroll
                for (int e = 0; e < 4; ++e) acc[rr][oh][e] = 0.f;

        // A-frags deduped: padded row 4w+dr serves all (rr,ky) with rr+ky==dr
        #pragma unroll
        for (int dr = 0; dr < 6; ++dr) {
            Frag A[3];
            const uint32_t* ap = Xs + (4 * q) * PL + (4 * w + dr) * RS + 16 * ch + n16;
            #pragma unroll
            for (int kx = 0; kx < 3; ++kx)
                #pragma unroll
                for (int p = 0; p < 4; ++p)
                    A[kx].u[p] = ap[p * PL + kx];
            #pragma unroll
            for (int ky = 0; ky < 3; ++ky) {
                const int rr = dr - ky;
                if (rr >= 0 && rr < 4) {
                    #pragma unroll
                    for (int kx = 0; kx < 3; ++kx) {
                        acc[rr][0] = __builtin_amdgcn_mfma_f32_16x16x32_bf16(
                                         A[kx].v, Bf[ky * 3 + kx][0].v, acc[rr][0], 0, 0, 0);
                        acc[rr][1] = __builtin_amdgcn_mfma_f32_16x16x32_bf16(
                                         A[kx].v, Bf[ky * 3 + kx][1].v, acc[rr][1], 0, 0, 0);
                    }
                }
            }
        }

        // ---- epilogue for this ch: plain float4 stores (L2 merges halves) ----
        #pragma unroll
        for (int oh = 0; oh < 2; ++oh) {
            const int oc = oh * 16 + n16;
            const float bv = oh ? bv1 : bv0;
            #pragma unroll
            for (int rr = 0; rr < 4; ++rr) {
                float4 v;
                v.x = acc[rr][oh][0] + bv;
                v.y = acc[rr][oh][1] + bv;
                v.z = acc[rr][oh][2] + bv;
                v.w = acc[rr][oh][3] + bv;
                *(float4*)&out[((size_t)(b * C + oc) * P + (y0 + 4 * w + rr)) * P
                               + x0 + 16 * ch + 4 * q] = v;
            }
        }
    }
}

extern "C" void kernel_launch(void* const* d_in, const int* in_sizes, int n_in,
                              void* d_out, int out_size, void* d_ws, size_t ws_size,
                              hipStream_t stream) {
    const float* x    = (const float*)d_in[0];
    const float* rbuf = (const float*)d_in[1];
    const float* bbuf = (const float*)d_in[2];
    const float* W    = (const float*)d_in[3];
    const float* bias = (const float*)d_in[4];
    float* out = (float*)d_out;
    uint32_t* wpk = (uint32_t*)d_ws;              // 18432 B used

    pack_w_kernel<<<9, 256, 0, stream>>>(W, wpk);
    conv_mfma<<<1024, 256, 0, stream>>>(x, rbuf, bbuf, wpk, bias, out);
}

// Round 7
// 130.627 us; speedup vs baseline: 1.7082x; 1.7082x over previous
//
#include <hip/hip_runtime.h>
#include <cstdint>

// StreamNet K3 S1 halo conv, bf16 MFMA implicit-GEMM.
// R12 = R11 geometry with R9's launch bounds (the only no-spill config).
// Toolchain lesson (R7/R10/R11, 3 strikes): ANY min-occupancy attribute >=3
// (launch_bounds min-waves or amdgpu_waves_per_eu) makes the scheduler chase
// even MORE occupancy than requested (allocates 64-84 VGPR vs ~116-reg live
// set) and spills ~60-140MB of scratch traffic. R9's plain
// __launch_bounds__(256,2) -> RA picks ~96 regs, zero scratch, 43.3us.
// R9's 2-blocks/CU cap was LDS-only (60KB). R12 keeps R9's structure and
// bounds, but LDS = 39168B (RS 36->34: no left-pad col; PL 612): 4 blocks/CU
// from LDS, and 96 VGPR allows 5 waves/EU -> occupancy doubles without any
// RA coercion. 4 staggered blocks/CU cover each other's compute tails
// (duty-cycle fix; R9 fact: fill kernel hits 6.3 TB/s at 8.7% occupancy,
// so the ~2.45 TB/s wall is duty cycle, not queue depth).
// Keeps: pack_w prologue (repack VALU + W traffic out of hot kernel,
// conflicts 1.5M->300K), 16x32 tiles (128B rows), grid 1024, XCD swizzle
// (batch i -> XCD i), ch-split MFMA sweep, plain f4 epilogue stores,
// W-loads-before-X-loads (FIFO vmcnt), b64 interior LDS stores.
//
// Padded input Xp[b][c][r][cc], r,cc in [0,258):
//   r < 2           -> bbuf[b][c][r][cc]           (bbuf [B][C][2][258])
//   r>=2, cc < 2    -> rbuf[b][c][r-2][cc]         (rbuf [B][C][256][2])
//   r>=2, cc>=2     -> (cc-2 == 255) ? 0 : x[b][c][r-2][cc-2]

constexpr int B  = 8;
constexpr int C  = 32;
constexpr int P  = 256;
constexpr int KB = 2;
constexpr int TH = 16;            // tile rows
constexpr int TW = 32;            // tile cols
constexpr int RS = 34;            // LDS row stride (dwords) == padded width, no pad col
constexpr int PL = 612;           // plane stride (dwords); 4q*612 mod 32 = {0,16} -> 2-way, free
constexpr int XSZ = 16 * PL;      // 9792 dwords = 39168 B -> 4 blocks/CU (low 4608 dw: W overlay)

typedef short bf16x8 __attribute__((ext_vector_type(8)));
typedef float f32x4  __attribute__((ext_vector_type(4)));
union Frag { uint32_t u[4]; bf16x8 v; };

static __device__ __forceinline__ uint32_t pk_bf16(float lo, float hi) {
    uint32_t a  = __builtin_bit_cast(uint32_t, lo);
    uint32_t b2 = __builtin_bit_cast(uint32_t, hi);
    a  += 0x7FFFu + ((a  >> 16) & 1u);
    b2 += 0x7FFFu + ((b2 >> 16) & 1u);
    return (a >> 16) | (b2 & 0xFFFF0000u);
}

// ---- prologue: pack W [C][C][3][3] f32 -> bf16-pair LDS image in d_ws ----
// image dword index: t*512 + oc*16 + icpair, halves (lo,hi) = ic (2m, 2m+1)
__global__ __launch_bounds__(256) void pack_w_kernel(
    const float* __restrict__ W, uint32_t* __restrict__ wpk)
{
    const int g = blockIdx.x * 256 + threadIdx.x;      // 0..2303
    const float4 v = ((const float4*)W)[g];
    const float vv[4] = { v.x, v.y, v.z, v.w };
    uint16_t* wh = (uint16_t*)wpk;
    #pragma unroll
    for (int e = 0; e < 4; ++e) {
        const int flat = 4 * g + e;                    // (oc*32+ic)*9 + t
        const int t    = flat % 9;
        const int rest = flat / 9;
        const int ic   = rest & 31;
        const int oc   = rest >> 5;
        const uint32_t u = __builtin_bit_cast(uint32_t, vv[e]);
        const uint16_t h = (uint16_t)((u + 0x7FFFu + ((u >> 16) & 1u)) >> 16);
        wh[(t * 512 + oc * 16 + (ic >> 1)) * 2 + (ic & 1)] = h;
    }
}

struct StP {                       // one plane-pair's staged data
    float4 a0, a1, c0, c1;         // interior: lo plane 8 cols, hi plane 8 cols
    float  h0l, h0h, h1l, h1h;     // 2 halo cells x (lo, hi)
};

__global__ __launch_bounds__(256, 2) void conv_mfma(
    const float* __restrict__ x,      // [B][C][P][P]
    const float* __restrict__ rbuf,   // [B][C][P][KB]
    const float* __restrict__ bbuf,   // [B][C][KB][P+KB]
    const uint32_t* __restrict__ wpk, // packed W image (4608 dwords)
    const float* __restrict__ bias,   // [C]
    float* __restrict__ out)          // [B][C][P][P]
{
    const int tid  = threadIdx.x;
    const int lane = tid & 63;
    const int w    = tid >> 6;        // wave 0..3
    const int q    = lane >> 4;
    const int n16  = lane & 15;

    // XCD swizzle: round-robin dispatch (blk%8 = XCD) -> XCD i gets swz
    // range [128i,128(i+1)) = all tiles of batch i (8.4MB x, in-XCD halos)
    const int swz = (blockIdx.x & 7) * 128 + (blockIdx.x >> 3);
    const int cx = swz & 7, ty = (swz >> 3) & 15, b = swz >> 7;
    const int x0 = cx * TW, y0 = ty * TH;

    __shared__ uint32_t Xs[XSZ];      // low 4608 dwords double as W region first

    // ---- staging lane geometry ----
    const int srow = lane >> 2;                    // 0..15
    const int scol = (lane & 3) * 8;               // 0,8,16,24 (8 cols/lane)
    const bool zc  = (x0 == P - TW) && ((lane & 3) == 3);   // col 255 in a1.w/c1.w

    // halo cells: 100 = top 2x34 (idx 0..67) + left 16x2 (idx 68..99)
    const float* xb = x    + (size_t)b * C * P * P;
    const float* rb = rbuf + (size_t)b * C * P * KB;
    const float* bb = bbuf + (size_t)b * C * KB * (P + KB);
    const float* basep[3] = { xb, rb, bb };
    const int    psz[3]   = { P * P, P * KB, KB * (P + KB) };

    int h_ldso[2], h_ps[2];
    const float* h_bp[2];
    bool h_z[2];
    #pragma unroll
    for (int ci = 0; ci < 2; ++ci) {
        const int c = lane + 64 * ci;
        int prow, pcol;
        if (c < 68) { const int hr = (c >= 34) ? 1 : 0; prow = hr; pcol = c - 34 * hr; }
        else        { const int cc = c - 68; prow = KB + (cc >> 1); pcol = cc & 1; }
        h_ldso[ci] = prow * RS + pcol;             // padded col pc at dword pc
        const int gr = y0 + prow, gc = x0 + pcol;
        int sel, off; bool z = false;
        if (gr < KB)      { sel = 2; off = gr * (P + KB) + gc; }
        else if (gc < KB) { sel = 1; off = (gr - KB) * KB + gc; }
        else              { sel = 0; off = (gr - KB) * P + (gc - KB); z = (gc == P + KB - 1); }
        h_bp[ci] = basep[sel] + off;
        h_ps[ci] = psz[sel];
        h_z[ci]  = z;
    }
    const bool h1a = lane < 36;                    // cell1 active

    // ---- 1. W image loads FIRST (their ds_write waits only on them) ----
    const uint4* wp4 = (const uint4*)wpk;          // 1152 uint4
    uint4 wv0 = wp4[tid];
    uint4 wv1 = wp4[256 + tid];
    uint4 wv2 = wp4[512 + tid];
    uint4 wv3 = wp4[768 + tid];
    uint4 wvt;
    const bool wtail = tid < 128;
    if (wtail) wvt = wp4[1024 + tid];
    const float bv0 = bias[n16];
    const float bv1 = bias[16 + n16];

    // ---- 2. issue ALL X loads (R9 structure: deep one-shot queue) ----
    StP S[4];
    #pragma unroll
    for (int k2 = 0; k2 < 4; ++k2) {
        const int m = 4 * k2 + w;
        const float* pi = xb + (size_t)(2 * m) * (P * P) + (y0 + srow) * P + x0 + scol;
        S[k2].a0 = *(const float4*)pi;
        S[k2].a1 = *(const float4*)(pi + 4);
        S[k2].c0 = *(const float4*)(pi + P * P);
        S[k2].c1 = *(const float4*)(pi + P * P + 4);
        const float* p0 = h_bp[0] + (size_t)(2 * m) * h_ps[0];
        S[k2].h0l = h_z[0] ? 0.f : p0[0];
        S[k2].h0h = h_z[0] ? 0.f : p0[h_ps[0]];
        if (h1a) {
            const float* p1 = h_bp[1] + (size_t)(2 * m) * h_ps[1];
            S[k2].h1l = h_z[1] ? 0.f : p1[0];
            S[k2].h1h = h_z[1] ? 0.f : p1[h_ps[1]];
        }
    }

    // ---- 3. W image -> LDS overlay (vmcnt waits only to W loads) ----
    uint4* xs4 = (uint4*)Xs;
    xs4[tid]       = wv0;
    xs4[256 + tid] = wv1;
    xs4[512 + tid] = wv2;
    xs4[768 + tid] = wv3;
    if (wtail) xs4[1024 + tid] = wvt;
    __syncthreads();

    // ---- 4. B fragments from overlay (X loads still draining) ----
    Frag Bf[9][2];
    #pragma unroll
    for (int t = 0; t < 9; ++t)
        #pragma unroll
        for (int oh = 0; oh < 2; ++oh)
            *(uint4*)Bf[t][oh].u =
                *(const uint4*)&Xs[t * 512 + (oh * 16 + n16) * 16 + q * 4];
    __syncthreads();              // overlay reads done; Xs reusable for X tile

    // ---- 5. pack + store X tiles (b64 stores: col offset 2 mod 4 dw) ----
    #pragma unroll
    for (int k2 = 0; k2 < 4; ++k2) {
        const int m = 4 * k2 + w;
        float4 a1 = S[k2].a1, c1 = S[k2].c1;
        if (zc) { a1.w = 0.f; c1.w = 0.f; }
        uint2 p0, p1, p2, p3;
        p0.x = pk_bf16(S[k2].a0.x, S[k2].c0.x); p0.y = pk_bf16(S[k2].a0.y, S[k2].c0.y);
        p1.x = pk_bf16(S[k2].a0.z, S[k2].c0.z); p1.y = pk_bf16(S[k2].a0.w, S[k2].c0.w);
        p2.x = pk_bf16(a1.x, c1.x);             p2.y = pk_bf16(a1.y, c1.y);
        p3.x = pk_bf16(a1.z, c1.z);             p3.y = pk_bf16(a1.w, c1.w);
        uint32_t* base = Xs + m * PL + (srow + KB) * RS + KB + scol;  // 8B aligned
        *(uint2*)(base + 0) = p0;
        *(uint2*)(base + 2) = p1;
        *(uint2*)(base + 4) = p2;
        *(uint2*)(base + 6) = p3;
        Xs[m * PL + h_ldso[0]] = pk_bf16(S[k2].h0l, S[k2].h0h);
        if (h1a) Xs[m * PL + h_ldso[1]] = pk_bf16(S[k2].h1l, S[k2].h1h);
    }
    __syncthreads();

    // ---- 6. MFMA sweep, split by column-half ch (acc stays 32 f32) ----
    #pragma unroll
    for (int ch = 0; ch < 2; ++ch) {
        f32x4 acc[4][2];
        #pragma unroll
        for (int rr = 0; rr < 4; ++rr)
            #pragma unroll
            for (int oh = 0; oh < 2; ++oh)
                #pragma unroll
                for (int e = 0; e < 4; ++e) acc[rr][oh][e] = 0.f;

        // A-frags deduped: padded row 4w+dr serves all (rr,ky) with rr+ky==dr
        #pragma unroll
        for (int dr = 0; dr < 6; ++dr) {
            Frag A[3];
            const uint32_t* ap = Xs + (4 * q) * PL + (4 * w + dr) * RS + 16 * ch + n16;
            #pragma unroll
            for (int kx = 0; kx < 3; ++kx)
                #pragma unroll
                for (int p = 0; p < 4; ++p)
                    A[kx].u[p] = ap[p * PL + kx];
            #pragma unroll
            for (int ky = 0; ky < 3; ++ky) {
                const int rr = dr - ky;
                if (rr >= 0 && rr < 4) {
                    #pragma unroll
                    for (int kx = 0; kx < 3; ++kx) {
                        acc[rr][0] = __builtin_amdgcn_mfma_f32_16x16x32_bf16(
                                         A[kx].v, Bf[ky * 3 + kx][0].v, acc[rr][0], 0, 0, 0);
                        acc[rr][1] = __builtin_amdgcn_mfma_f32_16x16x32_bf16(
                                         A[kx].v, Bf[ky * 3 + kx][1].v, acc[rr][1], 0, 0, 0);
                    }
                }
            }
        }

        // ---- epilogue for this ch: plain float4 stores (L2 merges halves) ----
        #pragma unroll
        for (int oh = 0; oh < 2; ++oh) {
            const int oc = oh * 16 + n16;
            const float bv = oh ? bv1 : bv0;
            #pragma unroll
            for (int rr = 0; rr < 4; ++rr) {
                float4 v;
                v.x = acc[rr][oh][0] + bv;
                v.y = acc[rr][oh][1] + bv;
                v.z = acc[rr][oh][2] + bv;
                v.w = acc[rr][oh][3] + bv;
                *(float4*)&out[((size_t)(b * C + oc) * P + (y0 + 4 * w + rr)) * P
                               + x0 + 16 * ch + 4 * q] = v;
            }
        }
    }
}

extern "C" void kernel_launch(void* const* d_in, const int* in_sizes, int n_in,
                              void* d_out, int out_size, void* d_ws, size_t ws_size,
                              hipStream_t stream) {
    const float* x    = (const float*)d_in[0];
    const float* rbuf = (const float*)d_in[1];
    const float* bbuf = (const float*)d_in[2];
    const float* W    = (const float*)d_in[3];
    const float* bias = (const float*)d_in[4];
    float* out = (float*)d_out;
    uint32_t* wpk = (uint32_t*)d_ws;              // 18432 B used

    pack_w_kernel<<<9, 256, 0, stream>>>(W, wpk);
    conv_mfma<<<1024, 256, 0, stream>>>(x, rbuf, bbuf, wpk, bias, out);
}